// Round 11
// baseline (463.620 us; speedup 1.0000x reference)
//
#include <hip/hip_runtime.h>
#include <hip/hip_fp16.h>
#include <math.h>

#define NN_ 2048
#define EE_ 4
#define CC_ 2
#define BB_ 16
#define SS_ 20
#define UU_ 256

// LSTM weight residency split (per-thread jp pairs: 128 for gate A, 80+48 for gate B)
#define LREGB 80
#define LLDSB 48

typedef __attribute__((ext_vector_type(8))) short short8;
typedef __attribute__((ext_vector_type(4))) float f32x4;
typedef _Float16 half2v __attribute__((ext_vector_type(2)));

__device__ __forceinline__ unsigned short f2bf(float x){
    union { float f; unsigned int u; } v; v.f = x;
    unsigned int u = v.u;
    unsigned int r = u + 0x7FFFu + ((u >> 16) & 1u);   // RNE
    return (unsigned short)(r >> 16);
}
__device__ __forceinline__ float bf2f(unsigned short s){
    union { unsigned int u; float f; } v; v.u = ((unsigned int)s) << 16; return v.f;
}

__device__ __forceinline__ half2v u2h2(unsigned int u){
    union { unsigned int u; half2v h; } c; c.u = u; return c.h;
}

// fused fp16 dot2 with fp32 accumulate (v_dot2_f32_f16), fallback to unpack+FMA
__device__ __forceinline__ float dot2f(unsigned int w, unsigned int h, float acc){
#if __has_builtin(__builtin_amdgcn_fdot2)
    return __builtin_amdgcn_fdot2(u2h2(w), u2h2(h), acc, false);
#else
    float w0 = __half2float(__ushort_as_half((unsigned short)(w & 0xffffu)));
    float w1 = __half2float(__ushort_as_half((unsigned short)(w >> 16)));
    float h0f = __half2float(__ushort_as_half((unsigned short)(h & 0xffffu)));
    float h1f = __half2float(__ushort_as_half((unsigned short)(h >> 16)));
    return fmaf(w1, h1f, fmaf(w0, h0f, acc));
#endif
}

__device__ __forceinline__ float sigf(float x){
    x = fminf(fmaxf(x, -30.f), 30.f);
    float e = __builtin_amdgcn_exp2f(-1.442695041f * x);
    return __builtin_amdgcn_rcpf(1.f + e);
}
__device__ __forceinline__ float tanhf_(float x){
    x = fminf(fmaxf(x, -15.f), 15.f);
    float e = __builtin_amdgcn_exp2f(2.885390082f * x);
    return (e - 1.f) * __builtin_amdgcn_rcpf(e + 1.f);
}

typedef const __attribute__((address_space(1))) unsigned int* gas_ptr;
typedef __attribute__((address_space(3))) unsigned int* las_ptr;
__device__ __forceinline__ void gl_lds16(const void* g, void* l){
    __builtin_amdgcn_global_load_lds((gas_ptr)g, (las_ptr)l, 16, 0, 0);
}

// ---------------- softmax of the three [C,E] weight rows ----------------
__global__ void k_softmax(const float* __restrict__ w1a, const float* __restrict__ w1b,
                          const float* __restrict__ w2, float* __restrict__ sm){
    int t = threadIdx.x;
    if (t < 6){
        int widx = t >> 1, c = t & 1;
        const float* w = (widx==0)? w1a : ((widx==1)? w1b : w2);
        float v[EE_]; float m = -1e30f;
        for (int e=0;e<EE_;e++){ v[e]=w[c*EE_+e]; m=fmaxf(m,v[e]); }
        float s=0.f;
        for (int e=0;e<EE_;e++){ v[e]=expf(v[e]-m); s+=v[e]; }
        for (int e=0;e<EE_;e++) sm[widx*8 + c*4 + e] = v[e]/s;
    }
}

// ---------------- conv materialization (bf16), one A pass ----------------
__global__ __launch_bounds__(256) void k_conv_bf16(const float4* __restrict__ A4,
        const float* __restrict__ sm, unsigned short* __restrict__ convA,
        unsigned short* __restrict__ convBT, unsigned short* __restrict__ convCT){
    __shared__ float4 tile[32][33];
    int bx = blockIdx.x*32, by = blockIdx.y*32;
    int tx = threadIdx.x & 31, ty = threadIdx.x >> 5;
    #pragma unroll
    for (int i=0;i<32;i+=8){
        int n = by+ty+i, m = bx+tx;
        float4 a = A4[(size_t)n*NN_ + m];
        tile[ty+i][tx] = a;
        #pragma unroll
        for (int cc=0;cc<CC_;cc++){
            const float* s = sm + cc*4;
            convA[(size_t)cc*NN_*NN_ + (size_t)n*NN_ + m] =
                f2bf(a.x*s[0]+a.y*s[1]+a.z*s[2]+a.w*s[3]);
        }
    }
    __syncthreads();
    #pragma unroll
    for (int i=0;i<32;i+=8){
        int x = bx+ty+i, y = by+tx;
        float4 a = tile[tx][ty+i];
        #pragma unroll
        for (int cc=0;cc<CC_;cc++){
            const float* s1 = sm + 8 + cc*4;
            const float* s2 = sm + 16 + cc*4;
            convBT[(size_t)cc*NN_*NN_ + (size_t)x*NN_ + y] =
                f2bf(a.x*s1[0]+a.y*s1[1]+a.z*s1[2]+a.w*s1[3]);
            convCT[(size_t)cc*NN_*NN_ + (size_t)x*NN_ + y] =
                f2bf(a.x*s2[0]+a.y*s2[1]+a.z*s2[2]+a.w*s2[3]);
        }
    }
}

// ---------------- bf16 MFMA GEMM: Cb[M][N] = bf16(A[M][K] * BT[N][K]^T) ----------------
// Fused epilogue: colacc[col] += sum_rows C[row][col]  (fp32, from accumulators)
__global__ __launch_bounds__(256) void k_mfma_gemm(const unsigned short* __restrict__ Abase,
        const unsigned short* __restrict__ Bbase, unsigned short* __restrict__ Cbase,
        float* __restrict__ colbase){
    const int c = blockIdx.z;
    const unsigned short* Ag = Abase + (size_t)c*NN_*NN_;
    const unsigned short* Bg = Bbase + (size_t)c*NN_*NN_;
    unsigned short* Cg = Cbase + (size_t)c*NN_*NN_;
    float* colacc = colbase + c*NN_;

    __shared__ __align__(16) unsigned short As[128*32];
    __shared__ __align__(16) unsigned short Bs[128*32];

    const int t = threadIdx.x;
    const int wave = t >> 6, lane = t & 63;
    const int m0 = blockIdx.y*128, n0 = blockIdx.x*128;
    const int wm = wave >> 1, wn = wave & 1;

    f32x4 acc[4][4];
    const f32x4 z = {0.f,0.f,0.f,0.f};
    #pragma unroll
    for (int i=0;i<4;i++)
        #pragma unroll
        for (int j=0;j<4;j++) acc[i][j] = z;

    const int srow = wave*32 + (lane>>2);
    const int scol = (lane&3)*8;
    const unsigned short* agp0 = Ag + (size_t)(m0+srow)*NN_ + scol;
    const unsigned short* agp1 = agp0 + (size_t)16*NN_;
    const unsigned short* bgp0 = Bg + (size_t)(n0+srow)*NN_ + scol;
    const unsigned short* bgp1 = bgp0 + (size_t)16*NN_;
    unsigned short* alp0 = &As[wave*1024];
    unsigned short* alp1 = &As[wave*1024 + 512];
    unsigned short* blp0 = &Bs[wave*1024];
    unsigned short* blp1 = &Bs[wave*1024 + 512];

    const int fr = lane & 15;
    const int fk = (lane >> 4) * 8;

    for (int k0=0; k0<NN_; k0+=32){
        gl_lds16(agp0, alp0);
        gl_lds16(agp1, alp1);
        gl_lds16(bgp0, blp0);
        gl_lds16(bgp1, blp1);
        agp0 += 32; agp1 += 32; bgp0 += 32; bgp1 += 32;
        __syncthreads();
        short8 af[4], bf[4];
        #pragma unroll
        for (int i=0;i<4;i++){
            af[i] = *(const short8*)&As[(wm*64 + i*16 + fr)*32 + fk];
            bf[i] = *(const short8*)&Bs[(wn*64 + i*16 + fr)*32 + fk];
        }
        #pragma unroll
        for (int i=0;i<4;i++)
            #pragma unroll
            for (int j=0;j<4;j++)
                acc[i][j] = __builtin_amdgcn_mfma_f32_16x16x32_bf16(af[i], bf[j], acc[i][j], 0, 0, 0);
        __syncthreads();
    }

    #pragma unroll
    for (int j=0;j<4;j++){
        int col = n0 + wn*64 + j*16 + (lane & 15);
        float cs = 0.f;
        #pragma unroll
        for (int i=0;i<4;i++){
            int row = m0 + wm*64 + i*16 + (lane>>4)*4;
            #pragma unroll
            for (int r=0;r<4;r++){
                Cg[(size_t)(row+r)*NN_ + col] = f2bf(acc[i][j][r]);
                cs += acc[i][j][r];
            }
        }
        atomicAdd(&colacc[col], cs);
    }
}

// ---------------- deg[m] = colsum[m] - diag(H)[m] (+1 if ADD); dinv in place ----------------
template<bool ADD>
__global__ void k_dinv(float* acc, const unsigned short* __restrict__ H){
    int id = blockIdx.x*256 + threadIdx.x;
    int c = id / NN_, m = id % NN_;
    float diag = bf2f(H[(size_t)c*NN_*NN_ + (size_t)m*NN_ + m]);
    float s = acc[id] - diag + (ADD ? 1.f : 0.f);
    acc[id] = (s==0.f) ? 0.f : 1.f/s;
}

// ---------------- Hn[c][m][k] = bf16((m==k?0:H1[m][k]) * dinv1[c][k])  (bf16 in/out) ----------------
__global__ __launch_bounds__(256) void k_hn(const unsigned short* __restrict__ H1,
        const float* __restrict__ dinv, unsigned short* __restrict__ Hn){
    int id = blockIdx.x*256 + threadIdx.x;       // over C*N*N/4
    int c = id >> 20;
    int rem = id & ((NN_*NN_/4)-1);
    int m = rem >> 9;
    int k4 = (rem & (NN_/4 - 1)) * 4;
    ushort4 h = *(const ushort4*)&H1[(size_t)c*NN_*NN_ + (size_t)m*NN_ + k4];
    float4 d = *(const float4*)&dinv[c*NN_ + k4];
    ushort4 o;
    o.x = f2bf((m==k4  ) ? 0.f : bf2f(h.x)*d.x);
    o.y = f2bf((m==k4+1) ? 0.f : bf2f(h.y)*d.y);
    o.z = f2bf((m==k4+2) ? 0.f : bf2f(h.z)*d.z);
    o.w = f2bf((m==k4+3) ? 0.f : bf2f(h.w)*d.w);
    *(ushort4*)&Hn[(size_t)c*NN_*NN_ + (size_t)m*NN_ + k4] = o;
}

// ---------------- Xw = X @ gcn_w ----------------
__global__ __launch_bounds__(256) void k_xw(const float* __restrict__ X, const float* __restrict__ W,
                                            float* __restrict__ Xw){
    __shared__ float Ws[64*64];
    int t = threadIdx.x;
    for (int i=t;i<4096;i+=256) Ws[i]=W[i];
    __syncthreads();
    int id = blockIdx.x*256 + t;
    int n = id >> 6, w = id & 63;
    float s = 0.f;
    #pragma unroll 8
    for (int j=0;j<64;j++) s = fmaf(X[n*64+j], Ws[j*64+w], s);
    Xw[id] = s;
}

// ---------------- Y[c][m][w] = sum_n H2[c][n][m] * Xw[n][w]  (H2 bf16) ----------------
__global__ __launch_bounds__(256) void k_gcn(const unsigned short* __restrict__ H2,
                                             const float* __restrict__ Xw, float* __restrict__ Y){
    int c = blockIdx.z;
    int m0 = blockIdx.y*64;
    int n0 = blockIdx.x*256;
    const unsigned short* Hc = H2 + (size_t)c*NN_*NN_;
    __shared__ float Hs[16][68];
    __shared__ float Xs[16][68];
    int t = threadIdx.x;
    int tm = t>>4, tn = t&15;
    float acc[4][4] = {};
    for (int nb=n0; nb<n0+256; nb+=16){
        int row = t>>4, c4 = (t&15)<<2;
        ushort4 h4 = *(const ushort4*)&Hc[(size_t)(nb+row)*NN_ + m0 + c4];
        Hs[row][c4+0]=bf2f(h4.x); Hs[row][c4+1]=bf2f(h4.y);
        Hs[row][c4+2]=bf2f(h4.z); Hs[row][c4+3]=bf2f(h4.w);
        *(float4*)&Xs[row][c4] = *(const float4*)&Xw[(nb+row)*64 + c4];
        __syncthreads();
        #pragma unroll
        for (int k=0;k<16;k++){
            float4 av = *(const float4*)&Hs[k][tm*4];
            float4 bv = *(const float4*)&Xs[k][tn*4];
            float a[4] = {av.x,av.y,av.z,av.w};
            float b[4] = {bv.x,bv.y,bv.z,bv.w};
            #pragma unroll
            for (int i=0;i<4;i++)
                #pragma unroll
                for (int j=0;j<4;j++)
                    acc[i][j] = fmaf(a[i], b[j], acc[i][j]);
        }
        __syncthreads();
    }
    #pragma unroll
    for (int i=0;i<4;i++)
        #pragma unroll
        for (int j=0;j<4;j++)
            atomicAdd(&Y[((size_t)c*NN_ + m0+tm*4+i)*64 + tn*4+j], acc[i][j]);
}

__global__ void k_gcn_epi(const float* __restrict__ Y, const unsigned short* __restrict__ H2,
                          const float* __restrict__ Xw, const float* __restrict__ dinv2,
                          float* __restrict__ Xcat){
    int id = blockIdx.x*256 + threadIdx.x;
    int c = id >> 17;
    int rem = id & 131071;
    int m = rem >> 6, w = rem & 63;
    float diag = bf2f(H2[(size_t)c*NN_*NN_ + (size_t)m*NN_ + m]);
    float xwv = Xw[m*64+w];
    float v = dinv2[c*NN_+m] * (Y[id] - diag*xwv + xwv);
    Xcat[m*128 + c*64 + w] = fmaxf(v, 0.f);
}

// ---------------- lin1 ----------------
__global__ __launch_bounds__(256) void k_lin1(const float* __restrict__ Xcat, const float* __restrict__ W,
                                              const float* __restrict__ b, float* __restrict__ Xf){
    __shared__ float WT[128*64];
    __shared__ float bs[64];
    int t = threadIdx.x;
    for (int i=t;i<8192;i+=256){ int o = i>>7, j = i&127; WT[j*64+o] = W[i]; }
    if (t<64) bs[t]=b[t];
    __syncthreads();
    int id = blockIdx.x*256 + t;
    int m = id>>6, o = id&63;
    float s = bs[o];
    #pragma unroll 8
    for (int j=0;j<128;j++) s = fmaf(Xcat[m*128+j], WT[j*64+o], s);
    Xf[id] = s;
}

// ---------------- ragged basket max-pool ----------------
__global__ __launch_bounds__(256) void k_pool(const int* __restrict__ seqs, const float* __restrict__ Xf,
                                              float* __restrict__ bask){
    int bs_id = blockIdx.x;
    __shared__ int idxbuf[NN_];
    __shared__ int cnt;
    __shared__ float red[4][64];
    int t = threadIdx.x;
    if (t==0) cnt=0;
    __syncthreads();
    const int* row = seqs + (size_t)bs_id*NN_;
    for (int i=t;i<NN_;i+=256){
        if (row[i] != 0){ int p = atomicAdd(&cnt,1); idxbuf[p]=i; }
    }
    __syncthreads();
    int nc = cnt;
    int g = t>>6, w = t&63;
    float mx = -INFINITY;
    for (int p=g;p<nc;p+=4) mx = fmaxf(mx, Xf[idxbuf[p]*64 + w]);
    red[g][w]=mx;
    __syncthreads();
    if (t<64){
        float m = fmaxf(fmaxf(red[0][t],red[1][t]),fmaxf(red[2][t],red[3][t]));
        bask[bs_id*64+t] = (nc>0)? m : 0.f;
    }
}

// ---------------- transpose ----------------
__global__ void k_transpose(const float* __restrict__ src, float* __restrict__ dst, int R, int Cc){
    __shared__ float tile[32][33];
    int bx = blockIdx.x*32, by = blockIdx.y*32;
    int tx = threadIdx.x, ty = threadIdx.y;
    #pragma unroll
    for (int i=0;i<32;i+=8) tile[ty+i][tx] = src[(size_t)(by+ty+i)*Cc + bx+tx];
    __syncthreads();
    #pragma unroll
    for (int i=0;i<32;i+=8) dst[(size_t)(bx+ty+i)*R + by+tx] = tile[tx][ty+i];
}

// ---------------- pack whh -> W2k[gate*256+u][jp] = f16x2{whh[g*256+u][2jp], [2jp+1]} ----------------
__global__ __launch_bounds__(256) void k_packw2(const float* __restrict__ whh, unsigned int* __restrict__ W2k){
    int id = blockIdx.x*256 + threadIdx.x;   // < 1024*128
    int rem = id >> 7;        // gate*256+u
    int jp  = id & 127;
    float2 v = *(const float2*)&whh[(size_t)rem*256 + 2*jp];
    unsigned int lo = __half_as_ushort(__float2half(v.x));
    unsigned int hi = __half_as_ushort(__float2half(v.y));
    W2k[id] = lo | (hi << 16);
}

// ---------------- G_ih ----------------
__global__ __launch_bounds__(256) void k_gih(const float* __restrict__ bask, const float* __restrict__ wihT,
                                             const float* __restrict__ bih, const float* __restrict__ bhh,
                                             float* __restrict__ G){
    int id = blockIdx.x*256 + threadIdx.x;
    int r = id >> 10, o = id & 1023;
    float s = bih[o] + bhh[o];
    #pragma unroll 8
    for (int j=0;j<64;j++) s = fmaf(bask[r*64+j], wihT[j*1024+o], s);
    G[id] = s;
}

// ---------------- LSTM v4: forced VGPR residency (launch_bounds(512,2)), static loop split ----------------
// thread (u, half): half0 computes gates i,f for unit u; half1 computes g,o.
__global__ __launch_bounds__(512, 2) void k_lstm4(const unsigned int* __restrict__ W2k,
        const float* __restrict__ G, const float* __restrict__ h0, const float* __restrict__ c0,
        const int* __restrict__ seqlen, float* __restrict__ actual){
    const int b = blockIdx.x;
    const int t = threadIdx.x;
    const int u = t & 255;
    const int half_ = t >> 8;
    const int g0 = 2*half_;        // i or g
    const int g1 = g0 + 1;         // f or o

    __shared__ unsigned int Wl[LLDSB][2][256];   // gate-B spillover jp=LREGB..127 (96 KB)
    __shared__ unsigned int hpk[128];            // h packed f16x2 along K
    __shared__ float xg[256], xo[256];

    // stage Wl[jj][hf][uu] = W2k[( (2*hf+1)*256 + uu )*128 + LREGB + jj]
    for (int k=0;k<LLDSB;k++){
        int idx = k*512 + t;
        int jj = idx >> 9, rem = idx & 511;
        int hf = rem >> 8, uu = rem & 255;
        ((unsigned int*)Wl)[idx] = W2k[(size_t)((2*hf+1)*256 + uu)*128 + LREGB + jj];
    }
    // preload registers (per-thread contiguous -> vectorizable)
    unsigned int wA[128], wB[LREGB];
    const unsigned int* pA = W2k + (size_t)(g0*256 + u)*128;
    const unsigned int* pB = W2k + (size_t)(g1*256 + u)*128;
    #pragma unroll
    for (int jp=0;jp<128;jp++) wA[jp] = pA[jp];
    #pragma unroll
    for (int jp=0;jp<LREGB;jp++) wB[jp] = pB[jp];

    float cv = 0.f;
    if (half_==0){
        cv = c0[b*256+u];
        ((__half*)hpk)[u] = __float2half(h0[b*256+u]);
    }
    int sl = seqlen[b]-1;
    int idx_b = sl<0?0:(sl>SS_-1?SS_-1:sl);
    __syncthreads();

    const float* gbase = G + (size_t)b*SS_*1024;
    for (int s=0;s<SS_;s++){
        float gA = gbase[s*1024 + g0*256 + u];   // issued early, used after dot loop
        float gB = gbase[s*1024 + g1*256 + u];
        float aA[4] = {0.f,0.f,0.f,0.f};
        float aB[4] = {0.f,0.f,0.f,0.f};
        // statically split: first LREGB jp use register wB, rest use LDS Wl
        #pragma unroll
        for (int jp=0;jp<LREGB;jp++){
            unsigned int hp = hpk[jp];
            aA[jp&3] = dot2f(wA[jp], hp, aA[jp&3]);
            aB[jp&3] = dot2f(wB[jp], hp, aB[jp&3]);
        }
        #pragma unroll
        for (int jp=LREGB;jp<128;jp++){
            unsigned int hp = hpk[jp];
            aA[jp&3] = dot2f(wA[jp], hp, aA[jp&3]);
            aB[jp&3] = dot2f(Wl[jp-LREGB][half_][u], hp, aB[jp&3]);
        }
        float accA = (aA[0]+aA[1]) + (aA[2]+aA[3]) + gA;
        float accB = (aB[0]+aB[1]) + (aB[2]+aB[3]) + gB;
        float iv = 0.f, fv = 0.f;
        if (half_){                       // g, o
            xg[u] = tanhf_(accA);
            xo[u] = sigf(accB);
        } else {                          // i, f
            iv = sigf(accA);
            fv = sigf(accB);
        }
        __syncthreads();
        if (!half_){
            cv = fv*cv + iv*xg[u];
            float hv = xo[u]*tanhf_(cv);
            if (s==idx_b) actual[b*256+u] = hv;
            ((__half*)hpk)[u] = __float2half(hv);
        }
        __syncthreads();
    }
}

// ---------------- final ----------------
__global__ __launch_bounds__(256) void k_final(const float* __restrict__ actual, const float* __restrict__ owT,
                                               float* __restrict__ out){
    __shared__ float as_[256];
    int t = threadIdx.x;
    int b = blockIdx.x >> 3;
    int i0 = (blockIdx.x & 7) * 256;
    as_[t] = actual[b*256+t];
    __syncthreads();
    int i = i0 + t;
    float s = 0.f;
    #pragma unroll 8
    for (int u=0;u<256;u++) s = fmaf(as_[u], owT[u*2048 + i], s);
    out[b*2048 + i] = 1.f/(1.f+expf(-s));
}

extern "C" void kernel_launch(void* const* d_in, const int* in_sizes, int n_in,
                              void* d_out, int out_size, void* d_ws, size_t ws_size,
                              hipStream_t stream){
    const float* A     = (const float*)d_in[0];
    const float* X     = (const float*)d_in[1];
    const int*   seqln = (const int*)  d_in[2];
    const int*   seqs  = (const int*)  d_in[3];
    const float* h0    = (const float*)d_in[4];
    const float* c0    = (const float*)d_in[5];
    const float* w1a   = (const float*)d_in[6];
    const float* w1b   = (const float*)d_in[7];
    const float* w2    = (const float*)d_in[8];
    const float* gcn_w = (const float*)d_in[9];
    const float* lin1w = (const float*)d_in[10];
    const float* lin1b = (const float*)d_in[11];
    const float* wih   = (const float*)d_in[12];
    const float* whh   = (const float*)d_in[13];
    const float* bih   = (const float*)d_in[14];
    const float* bhh   = (const float*)d_in[15];
    const float* out_w = (const float*)d_in[16];
    float* out = (float*)d_out;

    char* ws = (char*)d_ws;
    size_t off = 0;
    auto alloc = [&](size_t bytes)->char*{
        char* p = ws + off; off += (bytes + 255) & ~(size_t)255; return p;
    };
    float* sm     = (float*)alloc(24*4);
    float* dinv1  = (float*)alloc(CC_*NN_*4);
    float* dinv2  = (float*)alloc(CC_*NN_*4);
    float* Xw     = (float*)alloc((size_t)NN_*64*4);
    float* Xcat   = (float*)alloc((size_t)NN_*128*4);
    float* Xf     = (float*)alloc((size_t)NN_*64*4);
    float* Ybuf   = (float*)alloc((size_t)CC_*NN_*64*4);
    float* bask   = (float*)alloc((size_t)BB_*SS_*64*4);
    float* Gih    = (float*)alloc((size_t)BB_*SS_*1024*4);
    unsigned int* W2k = (unsigned int*)alloc((size_t)1024*128*4);
    float* wihT   = (float*)alloc((size_t)64*1024*4);
    float* owT    = (float*)alloc((size_t)256*2048*4);
    float* actual = (float*)alloc((size_t)BB_*UU_*4);
    unsigned short* convA  = (unsigned short*)alloc((size_t)CC_*NN_*NN_*2);
    unsigned short* convBT = (unsigned short*)alloc((size_t)CC_*NN_*NN_*2);
    unsigned short* convCT = (unsigned short*)alloc((size_t)CC_*NN_*NN_*2);
    unsigned short* HnB    = (unsigned short*)alloc((size_t)CC_*NN_*NN_*2);
    unsigned short* H1b    = (unsigned short*)alloc((size_t)CC_*NN_*NN_*2);
    unsigned short* H2b    = convA;   // reuse convA (dead after GEMM1), 16.8 MB

    hipMemsetAsync(dinv1, 0, CC_*NN_*4, stream);
    hipMemsetAsync(dinv2, 0, CC_*NN_*4, stream);
    hipMemsetAsync(Ybuf,  0, (size_t)CC_*NN_*64*4, stream);

    k_softmax<<<1,64,0,stream>>>(w1a,w1b,w2,sm);
    k_conv_bf16<<<dim3(64,64),256,0,stream>>>((const float4*)A, sm, convA, convBT, convCT);
    // H1 = convA @ convB   (bf16 out + fused colsum -> dinv1)
    k_mfma_gemm<<<dim3(16,16,2),256,0,stream>>>(convA, convBT, H1b, dinv1);
    k_dinv<false><<<CC_*NN_/256,256,0,stream>>>(dinv1, H1b);
    k_hn<<<CC_*NN_*NN_/4/256,256,0,stream>>>(H1b, dinv1, HnB);
    // H2 = Hn @ conv(w2)   (bf16 out + fused colsum -> dinv2)
    k_mfma_gemm<<<dim3(16,16,2),256,0,stream>>>(HnB, convCT, H2b, dinv2);
    k_dinv<true><<<CC_*NN_/256,256,0,stream>>>(dinv2, H2b);
    // GCN
    k_xw<<<NN_*64/256,256,0,stream>>>(X, gcn_w, Xw);
    k_gcn<<<dim3(8,32,2),256,0,stream>>>(H2b, Xw, Ybuf);
    k_gcn_epi<<<CC_*NN_*64/256,256,0,stream>>>(Ybuf, H2b, Xw, dinv2, Xcat);
    k_lin1<<<NN_*64/256,256,0,stream>>>(Xcat, lin1w, lin1b, Xf);
    k_pool<<<BB_*SS_,256,0,stream>>>(seqs, Xf, bask);
    // LSTM prep
    k_packw2<<<1024*128/256,256,0,stream>>>(whh, W2k);
    k_transpose<<<dim3(64/32, 1024/32),dim3(32,8),0,stream>>>(wih,  wihT, 1024, 64);
    k_transpose<<<dim3(256/32,2048/32),dim3(32,8),0,stream>>>(out_w, owT, 2048, 256);
    k_gih<<<BB_*SS_*1024/256,256,0,stream>>>(bask, wihT, bih, bhh, Gih);
    k_lstm4<<<BB_,512,0,stream>>>(W2k, Gih, h0, c0, seqln, actual);
    k_final<<<BB_*2048/256,256,0,stream>>>(actual, owT, out);
}

// Round 13
// 405.491 us; speedup vs baseline: 1.1434x; 1.1434x over previous
//
#include <hip/hip_runtime.h>
#include <hip/hip_fp16.h>
#include <math.h>

#define NN_ 2048
#define EE_ 4
#define CC_ 2
#define BB_ 16
#define SS_ 20
#define UU_ 256

// LSTM weight residency split (per-thread jp pairs: 128 for gate A, 80+48 for gate B)
#define LREGB 80
#define LLDSB 48

typedef __attribute__((ext_vector_type(8))) short short8;
typedef __attribute__((ext_vector_type(4))) float f32x4;
typedef _Float16 half2v __attribute__((ext_vector_type(2)));

__device__ __forceinline__ unsigned short f2bf(float x){
    union { float f; unsigned int u; } v; v.f = x;
    unsigned int u = v.u;
    unsigned int r = u + 0x7FFFu + ((u >> 16) & 1u);   // RNE
    return (unsigned short)(r >> 16);
}
__device__ __forceinline__ float bf2f(unsigned short s){
    union { unsigned int u; float f; } v; v.u = ((unsigned int)s) << 16; return v.f;
}

__device__ __forceinline__ half2v u2h2(unsigned int u){
    union { unsigned int u; half2v h; } c; c.u = u; return c.h;
}

// fused fp16 dot2 with fp32 accumulate (v_dot2_f32_f16), fallback to unpack+FMA
__device__ __forceinline__ float dot2f(unsigned int w, unsigned int h, float acc){
#if __has_builtin(__builtin_amdgcn_fdot2)
    return __builtin_amdgcn_fdot2(u2h2(w), u2h2(h), acc, false);
#else
    float w0 = __half2float(__ushort_as_half((unsigned short)(w & 0xffffu)));
    float w1 = __half2float(__ushort_as_half((unsigned short)(w >> 16)));
    float h0f = __half2float(__ushort_as_half((unsigned short)(h & 0xffffu)));
    float h1f = __half2float(__ushort_as_half((unsigned short)(h >> 16)));
    return fmaf(w1, h1f, fmaf(w0, h0f, acc));
#endif
}

__device__ __forceinline__ float sigf(float x){
    x = fminf(fmaxf(x, -30.f), 30.f);
    float e = __builtin_amdgcn_exp2f(-1.442695041f * x);
    return __builtin_amdgcn_rcpf(1.f + e);
}
__device__ __forceinline__ float tanhf_(float x){
    x = fminf(fmaxf(x, -15.f), 15.f);
    float e = __builtin_amdgcn_exp2f(2.885390082f * x);
    return (e - 1.f) * __builtin_amdgcn_rcpf(e + 1.f);
}

typedef const __attribute__((address_space(1))) unsigned int* gas_ptr;
typedef __attribute__((address_space(3))) unsigned int* las_ptr;
__device__ __forceinline__ void gl_lds16(const void* g, void* l){
    __builtin_amdgcn_global_load_lds((gas_ptr)g, (las_ptr)l, 16, 0, 0);
}

// 4-wide softmax helper
__device__ __forceinline__ void sm4(const float* __restrict__ w, int c, float* o){
    float v0=w[c*4], v1=w[c*4+1], v2=w[c*4+2], v3=w[c*4+3];
    float m = fmaxf(fmaxf(v0,v1), fmaxf(v2,v3));
    float e0=expf(v0-m), e1=expf(v1-m), e2=expf(v2-m), e3=expf(v3-m);
    float r = 1.f/(e0+e1+e2+e3);
    o[0]=e0*r; o[1]=e1*r; o[2]=e2*r; o[3]=e3*r;
}

// ---------------- conv materialization (bf16), one A pass, inline edge-softmax ----------------
__global__ __launch_bounds__(256) void k_conv_bf16(const float4* __restrict__ A4,
        const float* __restrict__ w1a, const float* __restrict__ w1b, const float* __restrict__ w2,
        unsigned short* __restrict__ convA, unsigned short* __restrict__ convBT,
        unsigned short* __restrict__ convCT){
    float smA[2][4], smB[2][4], smC[2][4];
    #pragma unroll
    for (int cc=0;cc<2;cc++){ sm4(w1a,cc,smA[cc]); sm4(w1b,cc,smB[cc]); sm4(w2,cc,smC[cc]); }

    __shared__ float4 tile[32][33];
    int bx = blockIdx.x*32, by = blockIdx.y*32;
    int tx = threadIdx.x & 31, ty = threadIdx.x >> 5;
    #pragma unroll
    for (int i=0;i<32;i+=8){
        int n = by+ty+i, m = bx+tx;
        float4 a = A4[(size_t)n*NN_ + m];
        tile[ty+i][tx] = a;
        #pragma unroll
        for (int cc=0;cc<CC_;cc++){
            const float* s = smA[cc];
            convA[(size_t)cc*NN_*NN_ + (size_t)n*NN_ + m] =
                f2bf(a.x*s[0]+a.y*s[1]+a.z*s[2]+a.w*s[3]);
        }
    }
    __syncthreads();
    #pragma unroll
    for (int i=0;i<32;i+=8){
        int x = bx+ty+i, y = by+tx;
        float4 a = tile[tx][ty+i];
        #pragma unroll
        for (int cc=0;cc<CC_;cc++){
            const float* s1 = smB[cc];
            const float* s2 = smC[cc];
            convBT[(size_t)cc*NN_*NN_ + (size_t)x*NN_ + y] =
                f2bf(a.x*s1[0]+a.y*s1[1]+a.z*s1[2]+a.w*s1[3]);
            convCT[(size_t)cc*NN_*NN_ + (size_t)x*NN_ + y] =
                f2bf(a.x*s2[0]+a.y*s2[1]+a.z*s2[2]+a.w*s2[3]);
        }
    }
}

// ---------------- bf16 MFMA GEMM v2: BK=64, XOR-swizzled LDS, XCD-swizzled blocks ----------------
// C[M][N] = A[M][K] * BT[N][K]^T ; C written bf16.
// LDS (row, chunk_lds) holds global (row, chunk_lds ^ (row&7)); reads apply the same XOR.
__global__ __launch_bounds__(256) void k_mfma_gemm(const unsigned short* __restrict__ Abase,
        const unsigned short* __restrict__ Bbase, unsigned short* __restrict__ Cbase){
    // XCD-aware swizzle: 512 wgs -> 8 XCDs x 64 contiguous tile ids (512 % 8 == 0, bijective)
    const int bid = blockIdx.x;
    const int nid = (bid & 7) * 64 + (bid >> 3);
    const int n0 = (nid & 15) * 128;
    const int m0 = ((nid >> 4) & 15) * 128;
    const int c  = nid >> 8;

    const unsigned short* Ag = Abase + (size_t)c*NN_*NN_;
    const unsigned short* Bg = Bbase + (size_t)c*NN_*NN_;
    unsigned short* Cg = Cbase + (size_t)c*NN_*NN_;

    __shared__ __align__(16) unsigned short As[128*64];   // 16 KB
    __shared__ __align__(16) unsigned short Bs[128*64];   // 16 KB

    const int t = threadIdx.x;
    const int wave = t >> 6, lane = t & 63;
    const int wm = wave >> 1, wn = wave & 1;

    f32x4 acc[4][4];
    const f32x4 z = {0.f,0.f,0.f,0.f};
    #pragma unroll
    for (int i=0;i<4;i++)
        #pragma unroll
        for (int j=0;j<4;j++) acc[i][j] = z;

    // staging: wave covers rows [wave*32, wave*32+32); instr k covers rows k*8..k*8+7
    const int lrow   = lane >> 3;                 // 0..7 row within 8-row group
    const int lchunk = lane & 7;                  // 0..7 16B chunk within 128B row
    const int gchunk = lchunk ^ lrow;             // source pre-swizzle (row&7 == lrow)
    const unsigned short* agp = Ag + (size_t)(m0 + wave*32 + lrow)*NN_ + gchunk*8;
    const unsigned short* bgp = Bg + (size_t)(n0 + wave*32 + lrow)*NN_ + gchunk*8;
    unsigned short* alp = &As[wave*32*64];
    unsigned short* blp = &Bs[wave*32*64];

    const int fr = lane & 15;
    const int hi = lane >> 4;
    const int sw = fr & 7;

    for (int k0=0; k0<NN_; k0+=64){
        #pragma unroll
        for (int k=0;k<4;k++){
            gl_lds16(agp + (size_t)k*8*NN_ + k0, alp + k*512);
            gl_lds16(bgp + (size_t)k*8*NN_ + k0, blp + k*512);
        }
        __syncthreads();
        short8 af[2][4], bf[2][4];
        #pragma unroll
        for (int i=0;i<4;i++){
            int rowA = (wm*64 + i*16 + fr)*64;
            int rowB = (wn*64 + i*16 + fr)*64;
            af[0][i] = *(const short8*)&As[rowA + ((hi    ) ^ sw)*8];
            af[1][i] = *(const short8*)&As[rowA + ((hi + 4) ^ sw)*8];
            bf[0][i] = *(const short8*)&Bs[rowB + ((hi    ) ^ sw)*8];
            bf[1][i] = *(const short8*)&Bs[rowB + ((hi + 4) ^ sw)*8];
        }
        #pragma unroll
        for (int kk=0;kk<2;kk++)
            #pragma unroll
            for (int i=0;i<4;i++)
                #pragma unroll
                for (int j=0;j<4;j++)
                    acc[i][j] = __builtin_amdgcn_mfma_f32_16x16x32_bf16(af[kk][i], bf[kk][j], acc[i][j], 0, 0, 0);
        __syncthreads();
    }

    #pragma unroll
    for (int i=0;i<4;i++){
        int row = m0 + wm*64 + i*16 + hi*4;
        #pragma unroll
        for (int j=0;j<4;j++){
            int col = n0 + wn*64 + j*16 + fr;
            #pragma unroll
            for (int r=0;r<4;r++)
                Cg[(size_t)(row+r)*NN_ + col] = f2bf(acc[i][j][r]);
        }
    }
}

// ---------------- column sums over bf16 H (ushort2-vectorized) ----------------
__global__ __launch_bounds__(256) void k_colsum_bf(const unsigned short* __restrict__ H,
                                                   float* __restrict__ acc){
    int c = blockIdx.z;
    int mp = blockIdx.x*256 + threadIdx.x;     // column pair index
    int nbeg = blockIdx.y*128;
    const unsigned short* Hc = H + (size_t)c*NN_*NN_;
    float s0 = 0.f, s1 = 0.f;
    for (int n=nbeg;n<nbeg+128;n++){
        ushort2 u = *(const ushort2*)&Hc[(size_t)n*NN_ + 2*mp];
        s0 += bf2f(u.x); s1 += bf2f(u.y);
    }
    atomicAdd(&acc[c*NN_ + 2*mp],     s0);
    atomicAdd(&acc[c*NN_ + 2*mp + 1], s1);
}

// ---------------- deg[m] = colsum[m] - diag(H)[m] (+1 if ADD); dinv in place ----------------
template<bool ADD>
__global__ void k_dinv(float* acc, const unsigned short* __restrict__ H){
    int id = blockIdx.x*256 + threadIdx.x;
    int c = id / NN_, m = id % NN_;
    float diag = bf2f(H[(size_t)c*NN_*NN_ + (size_t)m*NN_ + m]);
    float s = acc[id] - diag + (ADD ? 1.f : 0.f);
    acc[id] = (s==0.f) ? 0.f : 1.f/s;
}

// ---------------- Hn[c][m][k] = bf16((m==k?0:H1[m][k]) * dinv1[c][k])  (bf16 in/out) ----------------
__global__ __launch_bounds__(256) void k_hn(const unsigned short* __restrict__ H1,
        const float* __restrict__ dinv, unsigned short* __restrict__ Hn){
    int id = blockIdx.x*256 + threadIdx.x;       // over C*N*N/4
    int c = id >> 20;
    int rem = id & ((NN_*NN_/4)-1);
    int m = rem >> 9;
    int k4 = (rem & (NN_/4 - 1)) * 4;
    ushort4 h = *(const ushort4*)&H1[(size_t)c*NN_*NN_ + (size_t)m*NN_ + k4];
    float4 d = *(const float4*)&dinv[c*NN_ + k4];
    ushort4 o;
    o.x = f2bf((m==k4  ) ? 0.f : bf2f(h.x)*d.x);
    o.y = f2bf((m==k4+1) ? 0.f : bf2f(h.y)*d.y);
    o.z = f2bf((m==k4+2) ? 0.f : bf2f(h.z)*d.z);
    o.w = f2bf((m==k4+3) ? 0.f : bf2f(h.w)*d.w);
    *(ushort4*)&Hn[(size_t)c*NN_*NN_ + (size_t)m*NN_ + k4] = o;
}

// ---------------- Xw = X @ gcn_w ----------------
__global__ __launch_bounds__(256) void k_xw(const float* __restrict__ X, const float* __restrict__ W,
                                            float* __restrict__ Xw){
    __shared__ float Ws[64*64];
    int t = threadIdx.x;
    for (int i=t;i<4096;i+=256) Ws[i]=W[i];
    __syncthreads();
    int id = blockIdx.x*256 + t;
    int n = id >> 6, w = id & 63;
    float s = 0.f;
    #pragma unroll 8
    for (int j=0;j<64;j++) s = fmaf(X[n*64+j], Ws[j*64+w], s);
    Xw[id] = s;
}

// ---------------- Y[c][m][w] = sum_n H2[c][n][m] * Xw[n][w]  (H2 bf16) ----------------
__global__ __launch_bounds__(256) void k_gcn(const unsigned short* __restrict__ H2,
                                             const float* __restrict__ Xw, float* __restrict__ Y){
    int c = blockIdx.z;
    int m0 = blockIdx.y*64;
    int n0 = blockIdx.x*256;
    const unsigned short* Hc = H2 + (size_t)c*NN_*NN_;
    __shared__ float Hs[16][68];
    __shared__ float Xs[16][68];
    int t = threadIdx.x;
    int tm = t>>4, tn = t&15;
    float acc[4][4] = {};
    for (int nb=n0; nb<n0+256; nb+=16){
        int row = t>>4, c4 = (t&15)<<2;
        ushort4 h4 = *(const ushort4*)&Hc[(size_t)(nb+row)*NN_ + m0 + c4];
        Hs[row][c4+0]=bf2f(h4.x); Hs[row][c4+1]=bf2f(h4.y);
        Hs[row][c4+2]=bf2f(h4.z); Hs[row][c4+3]=bf2f(h4.w);
        *(float4*)&Xs[row][c4] = *(const float4*)&Xw[(nb+row)*64 + c4];
        __syncthreads();
        #pragma unroll
        for (int k=0;k<16;k++){
            float4 av = *(const float4*)&Hs[k][tm*4];
            float4 bv = *(const float4*)&Xs[k][tn*4];
            float a[4] = {av.x,av.y,av.z,av.w};
            float b[4] = {bv.x,bv.y,bv.z,bv.w};
            #pragma unroll
            for (int i=0;i<4;i++)
                #pragma unroll
                for (int j=0;j<4;j++)
                    acc[i][j] = fmaf(a[i], b[j], acc[i][j]);
        }
        __syncthreads();
    }
    #pragma unroll
    for (int i=0;i<4;i++)
        #pragma unroll
        for (int j=0;j<4;j++)
            atomicAdd(&Y[((size_t)c*NN_ + m0+tm*4+i)*64 + tn*4+j], acc[i][j]);
}

__global__ void k_gcn_epi(const float* __restrict__ Y, const unsigned short* __restrict__ H2,
                          const float* __restrict__ Xw, const float* __restrict__ dinv2,
                          float* __restrict__ Xcat){
    int id = blockIdx.x*256 + threadIdx.x;
    int c = id >> 17;
    int rem = id & 131071;
    int m = rem >> 6, w = rem & 63;
    float diag = bf2f(H2[(size_t)c*NN_*NN_ + (size_t)m*NN_ + m]);
    float xwv = Xw[m*64+w];
    float v = dinv2[c*NN_+m] * (Y[id] - diag*xwv + xwv);
    Xcat[m*128 + c*64 + w] = fmaxf(v, 0.f);
}

// ---------------- lin1 ----------------
__global__ __launch_bounds__(256) void k_lin1(const float* __restrict__ Xcat, const float* __restrict__ W,
                                              const float* __restrict__ b, float* __restrict__ Xf){
    __shared__ float WT[128*64];
    __shared__ float bs[64];
    int t = threadIdx.x;
    for (int i=t;i<8192;i+=256){ int o = i>>7, j = i&127; WT[j*64+o] = W[i]; }
    if (t<64) bs[t]=b[t];
    __syncthreads();
    int id = blockIdx.x*256 + t;
    int m = id>>6, o = id&63;
    float s = bs[o];
    #pragma unroll 8
    for (int j=0;j<128;j++) s = fmaf(Xcat[m*128+j], WT[j*64+o], s);
    Xf[id] = s;
}

// ---------------- ragged basket max-pool ----------------
__global__ __launch_bounds__(256) void k_pool(const int* __restrict__ seqs, const float* __restrict__ Xf,
                                              float* __restrict__ bask){
    int bs_id = blockIdx.x;
    __shared__ int idxbuf[NN_];
    __shared__ int cnt;
    __shared__ float red[4][64];
    int t = threadIdx.x;
    if (t==0) cnt=0;
    __syncthreads();
    const int* row = seqs + (size_t)bs_id*NN_;
    for (int i=t;i<NN_;i+=256){
        if (row[i] != 0){ int p = atomicAdd(&cnt,1); idxbuf[p]=i; }
    }
    __syncthreads();
    int nc = cnt;
    int g = t>>6, w = t&63;
    float mx = -INFINITY;
    for (int p=g;p<nc;p+=4) mx = fmaxf(mx, Xf[idxbuf[p]*64 + w]);
    red[g][w]=mx;
    __syncthreads();
    if (t<64){
        float m = fmaxf(fmaxf(red[0][t],red[1][t]),fmaxf(red[2][t],red[3][t]));
        bask[bs_id*64+t] = (nc>0)? m : 0.f;
    }
}

// ---------------- transpose ----------------
__global__ void k_transpose(const float* __restrict__ src, float* __restrict__ dst, int R, int Cc){
    __shared__ float tile[32][33];
    int bx = blockIdx.x*32, by = blockIdx.y*32;
    int tx = threadIdx.x, ty = threadIdx.y;
    #pragma unroll
    for (int i=0;i<32;i+=8) tile[ty+i][tx] = src[(size_t)(by+ty+i)*Cc + bx+tx];
    __syncthreads();
    #pragma unroll
    for (int i=0;i<32;i+=8) dst[(size_t)(bx+ty+i)*R + by+tx] = tile[tx][ty+i];
}

// ---------------- pack whh -> W2k[gate*256+u][jp] = f16x2{whh[g*256+u][2jp], [2jp+1]} ----------------
__global__ __launch_bounds__(256) void k_packw2(const float* __restrict__ whh, unsigned int* __restrict__ W2k){
    int id = blockIdx.x*256 + threadIdx.x;   // < 1024*128
    int rem = id >> 7;        // gate*256+u
    int jp  = id & 127;
    float2 v = *(const float2*)&whh[(size_t)rem*256 + 2*jp];
    unsigned int lo = __half_as_ushort(__float2half(v.x));
    unsigned int hi = __half_as_ushort(__float2half(v.y));
    W2k[id] = lo | (hi << 16);
}

// ---------------- G_ih ----------------
__global__ __launch_bounds__(256) void k_gih(const float* __restrict__ bask, const float* __restrict__ wihT,
                                             const float* __restrict__ bih, const float* __restrict__ bhh,
                                             float* __restrict__ G){
    int id = blockIdx.x*256 + threadIdx.x;
    int r = id >> 10, o = id & 1023;
    float s = bih[o] + bhh[o];
    #pragma unroll 8
    for (int j=0;j<64;j++) s = fmaf(bask[r*64+j], wihT[j*1024+o], s);
    G[id] = s;
}

// ---------------- LSTM v4: forced VGPR residency (launch_bounds(512,2)), static loop split ----------------
__global__ __launch_bounds__(512, 2) void k_lstm4(const unsigned int* __restrict__ W2k,
        const float* __restrict__ G, const float* __restrict__ h0, const float* __restrict__ c0,
        const int* __restrict__ seqlen, float* __restrict__ actual){
    const int b = blockIdx.x;
    const int t = threadIdx.x;
    const int u = t & 255;
    const int half_ = t >> 8;
    const int g0 = 2*half_;        // i or g
    const int g1 = g0 + 1;         // f or o

    __shared__ unsigned int Wl[LLDSB][2][256];   // gate-B spillover jp=LREGB..127 (96 KB)
    __shared__ unsigned int hpk[128];            // h packed f16x2 along K
    __shared__ float xg[256], xo[256];

    for (int k=0;k<LLDSB;k++){
        int idx = k*512 + t;
        int jj = idx >> 9, rem = idx & 511;
        int hf = rem >> 8, uu = rem & 255;
        ((unsigned int*)Wl)[idx] = W2k[(size_t)((2*hf+1)*256 + uu)*128 + LREGB + jj];
    }
    unsigned int wA[128], wB[LREGB];
    const unsigned int* pA = W2k + (size_t)(g0*256 + u)*128;
    const unsigned int* pB = W2k + (size_t)(g1*256 + u)*128;
    #pragma unroll
    for (int jp=0;jp<128;jp++) wA[jp] = pA[jp];
    #pragma unroll
    for (int jp=0;jp<LREGB;jp++) wB[jp] = pB[jp];

    float cv = 0.f;
    if (half_==0){
        cv = c0[b*256+u];
        ((__half*)hpk)[u] = __float2half(h0[b*256+u]);
    }
    int sl = seqlen[b]-1;
    int idx_b = sl<0?0:(sl>SS_-1?SS_-1:sl);
    __syncthreads();

    const float* gbase = G + (size_t)b*SS_*1024;
    for (int s=0;s<SS_;s++){
        float gA = gbase[s*1024 + g0*256 + u];
        float gB = gbase[s*1024 + g1*256 + u];
        float aA[4] = {0.f,0.f,0.f,0.f};
        float aB[4] = {0.f,0.f,0.f,0.f};
        #pragma unroll
        for (int jp=0;jp<LREGB;jp++){
            unsigned int hp = hpk[jp];
            aA[jp&3] = dot2f(wA[jp], hp, aA[jp&3]);
            aB[jp&3] = dot2f(wB[jp], hp, aB[jp&3]);
        }
        #pragma unroll
        for (int jp=LREGB;jp<128;jp++){
            unsigned int hp = hpk[jp];
            aA[jp&3] = dot2f(wA[jp], hp, aA[jp&3]);
            aB[jp&3] = dot2f(Wl[jp-LREGB][half_][u], hp, aB[jp&3]);
        }
        float accA = (aA[0]+aA[1]) + (aA[2]+aA[3]) + gA;
        float accB = (aB[0]+aB[1]) + (aB[2]+aB[3]) + gB;
        float iv = 0.f, fv = 0.f;
        if (half_){                       // g, o
            xg[u] = tanhf_(accA);
            xo[u] = sigf(accB);
        } else {                          // i, f
            iv = sigf(accA);
            fv = sigf(accB);
        }
        __syncthreads();
        if (!half_){
            cv = fv*cv + iv*xg[u];
            float hv = xo[u]*tanhf_(cv);
            if (s==idx_b) actual[b*256+u] = hv;
            ((__half*)hpk)[u] = __float2half(hv);
        }
        __syncthreads();
    }
}

// ---------------- final ----------------
__global__ __launch_bounds__(256) void k_final(const float* __restrict__ actual, const float* __restrict__ owT,
                                               float* __restrict__ out){
    __shared__ float as_[256];
    int t = threadIdx.x;
    int b = blockIdx.x >> 3;
    int i0 = (blockIdx.x & 7) * 256;
    as_[t] = actual[b*256+t];
    __syncthreads();
    int i = i0 + t;
    float s = 0.f;
    #pragma unroll 8
    for (int u=0;u<256;u++) s = fmaf(as_[u], owT[u*2048 + i], s);
    out[b*2048 + i] = 1.f/(1.f+expf(-s));
}

extern "C" void kernel_launch(void* const* d_in, const int* in_sizes, int n_in,
                              void* d_out, int out_size, void* d_ws, size_t ws_size,
                              hipStream_t stream){
    const float* A     = (const float*)d_in[0];
    const float* X     = (const float*)d_in[1];
    const int*   seqln = (const int*)  d_in[2];
    const int*   seqs  = (const int*)  d_in[3];
    const float* h0    = (const float*)d_in[4];
    const float* c0    = (const float*)d_in[5];
    const float* w1a   = (const float*)d_in[6];
    const float* w1b   = (const float*)d_in[7];
    const float* w2    = (const float*)d_in[8];
    const float* gcn_w = (const float*)d_in[9];
    const float* lin1w = (const float*)d_in[10];
    const float* lin1b = (const float*)d_in[11];
    const float* wih   = (const float*)d_in[12];
    const float* whh   = (const float*)d_in[13];
    const float* bih   = (const float*)d_in[14];
    const float* bhh   = (const float*)d_in[15];
    const float* out_w = (const float*)d_in[16];
    float* out = (float*)d_out;

    char* ws = (char*)d_ws;
    size_t off = 0;
    auto alloc = [&](size_t bytes)->char*{
        char* p = ws + off; off += (bytes + 255) & ~(size_t)255; return p;
    };
    float* dinv1  = (float*)alloc(CC_*NN_*4);
    float* dinv2  = (float*)alloc(CC_*NN_*4);
    float* Xw     = (float*)alloc((size_t)NN_*64*4);
    float* Xcat   = (float*)alloc((size_t)NN_*128*4);
    float* Xf     = (float*)alloc((size_t)NN_*64*4);
    float* Ybuf   = (float*)alloc((size_t)CC_*NN_*64*4);
    float* bask   = (float*)alloc((size_t)BB_*SS_*64*4);
    float* Gih    = (float*)alloc((size_t)BB_*SS_*1024*4);
    unsigned int* W2k = (unsigned int*)alloc((size_t)1024*128*4);
    float* wihT   = (float*)alloc((size_t)64*1024*4);
    float* owT    = (float*)alloc((size_t)256*2048*4);
    float* actual = (float*)alloc((size_t)BB_*UU_*4);
    unsigned short* convA  = (unsigned short*)alloc((size_t)CC_*NN_*NN_*2);
    unsigned short* convBT = (unsigned short*)alloc((size_t)CC_*NN_*NN_*2);
    unsigned short* convCT = (unsigned short*)alloc((size_t)CC_*NN_*NN_*2);
    unsigned short* HnB    = (unsigned short*)alloc((size_t)CC_*NN_*NN_*2);
    unsigned short* H1b    = (unsigned short*)alloc((size_t)CC_*NN_*NN_*2);
    unsigned short* H2b    = convA;   // reuse convA (dead after GEMM1)

    hipMemsetAsync(dinv1, 0, CC_*NN_*4, stream);
    hipMemsetAsync(dinv2, 0, CC_*NN_*4, stream);
    hipMemsetAsync(Ybuf,  0, (size_t)CC_*NN_*64*4, stream);

    k_conv_bf16<<<dim3(64,64),256,0,stream>>>((const float4*)A, w1a, w1b, w2, convA, convBT, convCT);
    // H1 = convA @ convB  (bf16 out)
    k_mfma_gemm<<<512,256,0,stream>>>(convA, convBT, H1b);
    k_colsum_bf<<<dim3(4,16,2),256,0,stream>>>(H1b, dinv1);
    k_dinv<false><<<CC_*NN_/256,256,0,stream>>>(dinv1, H1b);
    k_hn<<<CC_*NN_*NN_/4/256,256,0,stream>>>(H1b, dinv1, HnB);
    // H2 = Hn @ conv(w2)  (bf16 out)
    k_mfma_gemm<<<512,256,0,stream>>>(HnB, convCT, H2b);
    k_colsum_bf<<<dim3(4,16,2),256,0,stream>>>(H2b, dinv2);
    k_dinv<true><<<CC_*NN_/256,256,0,stream>>>(dinv2, H2b);
    // GCN
    k_xw<<<NN_*64/256,256,0,stream>>>(X, gcn_w, Xw);
    k_gcn<<<dim3(8,32,2),256,0,stream>>>(H2b, Xw, Ybuf);
    k_gcn_epi<<<CC_*NN_*64/256,256,0,stream>>>(Ybuf, H2b, Xw, dinv2, Xcat);
    k_lin1<<<NN_*64/256,256,0,stream>>>(Xcat, lin1w, lin1b, Xf);
    k_pool<<<BB_*SS_,256,0,stream>>>(seqs, Xf, bask);
    // LSTM prep
    k_packw2<<<1024*128/256,256,0,stream>>>(whh, W2k);
    k_transpose<<<dim3(64/32, 1024/32),dim3(32,8),0,stream>>>(wih,  wihT, 1024, 64);
    k_transpose<<<dim3(256/32,2048/32),dim3(32,8),0,stream>>>(out_w, owT, 2048, 256);
    k_gih<<<BB_*SS_*1024/256,256,0,stream>>>(bask, wihT, bih, bhh, Gih);
    k_lstm4<<<BB_,512,0,stream>>>(W2k, Gih, h0, c0, seqln, actual);
    k_final<<<BB_*2048/256,256,0,stream>>>(actual, owT, out);
}